// Round 8
// baseline (146.401 us; speedup 1.0000x reference)
//
#include <hip/hip_runtime.h>
#include <hip/hip_bf16.h>

// B=4, S=256, H=768, P=54.
// out[b,i,j,p] = valid ? relu(ha[b,i]+hb[b,j]+bp1) . Wp2[p] + bp2[p] : 0
// valid = cand[i] & cand[j] & i!=j; cand = (relu(x W1^T + b1) . W2[0] + b2[0]) > 0.5
// cand rate ~1% -> sparse pairs.
// R1: per-CU-BW-bound hab -> k-split. R2: split-K=4 gemm (768 blk), stride-68 LDS.
// R3: 139.8. R4/R5: multi-change regressions (R5's 96-blk hab = occupancy cliff).
// R6: coop grid.sync fusion = 340us disaster (XCD-L2 non-coherence). Never again.
// R7: 137.5 BEST — R3 + counter-zero folded into gemm_k (-2.3us).
// R8: ONE change — replace memset-out + pairs + pair with R5's fused pair_kernel
//     (per-block self-zero of disjoint out regions + LDS scan + compute).
//     Removes 9us serialized memset + 2 dispatch gaps. 6 -> 4 dispatches.

#define M_ROWS 1024
#define HDIM 768
#define PDIM 54
#define MAXC 256            // candidate slot cap (actual nc ~27)
#define KCHUNK 16
#define NKC (HDIM / KCHUNK) // 48
#define KSPLIT 4
#define KSEG (HDIM / KSPLIT) // 192

// ---- workspace layout (bytes) ----
#define CANDCNT_OFF  0
#define CANDIDX_OFF  8192        // MAXC int
#define CANDSLOT_OFF 12288       // 1024 int (fully written each call)
#define HPART_OFF    1064960     // KSPLIT*1024*768 f32 = 12 MB

// ================= split-K GEMM (R7-proven) =================
// 64x64 tile, K-seg 192, 256 thr, 4x4 micro. hpart[z][m][n] = partial x.W1^T.
// Block (0,0,0) thread 0 also zeroes candCnt (ws is 0xAA-poisoned).
__global__ __launch_bounds__(256) void gemm_k_kernel(
    const float* __restrict__ x, const float* __restrict__ W1,
    float* __restrict__ hpart, int* __restrict__ counters)
{
    __shared__ float As[16][68];
    __shared__ float Bs[16][68];

    if (blockIdx.x == 0 && blockIdx.y == 0 && blockIdx.z == 0 && threadIdx.x == 0)
        counters[0] = 0;

    const int m0 = blockIdx.x * 64;
    const int n0 = blockIdx.y * 64;
    const int kb = blockIdx.z * KSEG;
    const int t  = threadIdx.x;
    const int tm = t & 15;
    const int tn = t >> 4;
    const int r  = t >> 2;        // 0..63
    const int c4 = (t & 3) * 4;   // 0,4,8,12

    float acc[4][4] = {};

    for (int k0 = kb; k0 < kb + KSEG; k0 += 16) {
        float4 av = *(const float4*)(x  + (size_t)(m0 + r) * HDIM + k0 + c4);
        float4 bv = *(const float4*)(W1 + (size_t)(n0 + r) * HDIM + k0 + c4);
        As[c4+0][r] = av.x; As[c4+1][r] = av.y; As[c4+2][r] = av.z; As[c4+3][r] = av.w;
        Bs[c4+0][r] = bv.x; Bs[c4+1][r] = bv.y; Bs[c4+2][r] = bv.z; Bs[c4+3][r] = bv.w;
        __syncthreads();
        #pragma unroll
        for (int kk = 0; kk < 16; ++kk) {
            float a[4], b[4];
            #pragma unroll
            for (int i = 0; i < 4; ++i) a[i] = As[kk][tm * 4 + i];
            #pragma unroll
            for (int j = 0; j < 4; ++j) b[j] = Bs[kk][tn * 4 + j];
            #pragma unroll
            for (int i = 0; i < 4; ++i)
                #pragma unroll
                for (int j = 0; j < 4; ++j)
                    acc[i][j] += a[i] * b[j];
        }
        __syncthreads();
    }

    float* dst = hpart + (size_t)blockIdx.z * (M_ROWS * HDIM);
    #pragma unroll
    for (int i = 0; i < 4; ++i) {
        float4 v = make_float4(acc[i][0], acc[i][1], acc[i][2], acc[i][3]);
        *(float4*)(dst + (size_t)(m0 + tm * 4 + i) * HDIM + n0 + tn * 4) = v;
    }
}

// reduce KSPLIT partials, relu.w2, decide cand. One block per row m. (R7-proven)
__global__ __launch_bounds__(256) void span_cand_kernel(
    const float* __restrict__ hpart, const float* __restrict__ b1,
    const float* __restrict__ w2row, const float* __restrict__ b2,
    int* __restrict__ candCount, int* __restrict__ candIdx,
    int* __restrict__ candSlot)
{
    const int m = blockIdx.x;
    const int t = threadIdx.x;
    float p = 0.f;
    for (int n = t; n < HDIM; n += 256) {
        float v = hpart[(size_t)m * HDIM + n]
                + hpart[(size_t)(M_ROWS * HDIM) + (size_t)m * HDIM + n]
                + hpart[(size_t)(2 * M_ROWS * HDIM) + (size_t)m * HDIM + n]
                + hpart[(size_t)(3 * M_ROWS * HDIM) + (size_t)m * HDIM + n];
        v += b1[n];
        v = v > 0.f ? v : 0.f;
        p += v * w2row[n];
    }
    __shared__ float wred[4];
    #pragma unroll
    for (int off = 32; off > 0; off >>= 1) p += __shfl_down(p, off, 64);
    if ((t & 63) == 0) wred[t >> 6] = p;
    __syncthreads();
    if (t == 0) {
        float s = wred[0] + wred[1] + wred[2] + wred[3] + b2[0];
        if (s > 0.5f) {
            int sl = atomicAdd(candCount, 1);
            if (sl < MAXC) { candIdx[sl] = m; candSlot[m] = sl; }
            else candSlot[m] = -1;
        } else {
            candSlot[m] = -1;
        }
    }
}

// ================= hab: k-split across blocks (R7-proven) =================
__global__ __launch_bounds__(256) void hab_kernel(
    const float* __restrict__ x, const float* __restrict__ Wp1,
    const int* __restrict__ candCount, const int* __restrict__ candIdx,
    float* __restrict__ ha, float* __restrict__ hb)
{
    __shared__ float xs[HDIM];
    __shared__ float red[2][KCHUNK][17];
    int nc = *candCount; if (nc > MAXC) nc = MAXC;
    const int nitems = nc * NKC;
    const int kk  = threadIdx.x >> 4;
    const int hb0 = (threadIdx.x & 15) * 4;

    for (int item = blockIdx.x; item < nitems; item += gridDim.x) {
        int slot = item / NKC;
        int kc   = item % NKC;
        int row  = candIdx[slot];

        for (int h = threadIdx.x; h < HDIM; h += 256)
            xs[h] = x[(size_t)row * HDIM + h];
        __syncthreads();

        int k = kc * KCHUNK + kk;
        const float* wr = Wp1 + (size_t)k * (2 * HDIM);
        float sa = 0.f, sb = 0.f;
        #pragma unroll
        for (int h = hb0; h < HDIM; h += 64) {
            float4 xv = *(const float4*)(xs + h);
            float4 wa = *(const float4*)(wr + h);
            float4 wb = *(const float4*)(wr + HDIM + h);
            sa += xv.x * wa.x + xv.y * wa.y + xv.z * wa.z + xv.w * wa.w;
            sb += xv.x * wb.x + xv.y * wb.y + xv.z * wb.z + xv.w * wb.w;
        }
        red[0][kk][threadIdx.x & 15] = sa;
        red[1][kk][threadIdx.x & 15] = sb;
        __syncthreads();

        if (threadIdx.x < 32) {
            int which = threadIdx.x >> 4;
            int kk2   = threadIdx.x & 15;
            float s = 0.f;
            #pragma unroll
            for (int g = 0; g < 16; ++g) s += red[which][kk2][g];
            float* dst = which == 0 ? ha : hb;
            dst[(size_t)slot * HDIM + kc * KCHUNK + kk2] = s;
        }
        __syncthreads();
    }
}

// ================= fused zero + pair scan + logits (R5-proven pattern) ======
// Each block OWNS pair-id range [bid*512, bid*512+512): zeroes its out region
// (disjoint across blocks), scans it for valid pairs, computes them.
// __syncthreads (vmcnt-drained) orders zero-stores before value-stores.
__global__ __launch_bounds__(256) void pair_kernel(
    const float* __restrict__ ha, const float* __restrict__ hb,
    const float* __restrict__ bp1, const float* __restrict__ Wp2,
    const float* __restrict__ bp2, const int* __restrict__ candSlot,
    float* __restrict__ out)
{
    __shared__ int plist[512];
    __shared__ int pcnt;
    __shared__ float v[HDIM];
    __shared__ float red[4][PDIM + 2];
    const int t = threadIdx.x;

    // zero own region: 512 pairs * 54 f32 = 6912 float4
    float* outb = out + (size_t)blockIdx.x * 512 * PDIM;
    float4 z = make_float4(0.f, 0.f, 0.f, 0.f);
    #pragma unroll
    for (int q = 0; q < 27; ++q)
        *(float4*)(outb + (size_t)(q * 256 + t) * 4) = z;

    if (t == 0) pcnt = 0;
    __syncthreads();

    #pragma unroll
    for (int q = 0; q < 2; ++q) {
        int idx = blockIdx.x * 512 + q * 256 + t;  // b*65536 + i*256 + j
        int b = idx >> 16;
        int i = (idx >> 8) & 255;
        int j = idx & 255;
        if (i != j && candSlot[b * 256 + i] >= 0 && candSlot[b * 256 + j] >= 0) {
            int p = atomicAdd(&pcnt, 1);
            plist[p] = idx;
        }
    }
    __syncthreads();   // drains zero-stores before any value-store
    const int np = pcnt;  // almost always 0 -> block exits after zeroing

    for (int p = 0; p < np; ++p) {
        int idx = plist[p];
        int b = idx >> 16;
        int i = (idx >> 8) & 255;
        int j = idx & 255;
        int si = candSlot[b * 256 + i];
        int sj = candSlot[b * 256 + j];
        if (t < 192) {
            float4 a4 = *(const float4*)(ha + (size_t)si * HDIM + t * 4);
            float4 b4 = *(const float4*)(hb + (size_t)sj * HDIM + t * 4);
            float4 c4 = *(const float4*)(bp1 + t * 4);
            float4 r;
            r.x = a4.x + b4.x + c4.x; r.x = r.x > 0.f ? r.x : 0.f;
            r.y = a4.y + b4.y + c4.y; r.y = r.y > 0.f ? r.y : 0.f;
            r.z = a4.z + b4.z + c4.z; r.z = r.z > 0.f ? r.z : 0.f;
            r.w = a4.w + b4.w + c4.w; r.w = r.w > 0.f ? r.w : 0.f;
            *(float4*)(v + t * 4) = r;
        }
        __syncthreads();
        if (t < 216) {
            int pp  = t % PDIM;
            int seg = t / PDIM;               // 0..3, h-range 192 each
            const float* w = Wp2 + (size_t)pp * HDIM + seg * 192;
            const float* vv = v + seg * 192;
            float s = 0.f;
            for (int h = 0; h < 192; h += 4) {
                float4 a = *(const float4*)(vv + h);
                float4 b2_ = *(const float4*)(w + h);
                s += a.x * b2_.x + a.y * b2_.y + a.z * b2_.z + a.w * b2_.w;
            }
            red[seg][pp] = s;
        }
        __syncthreads();
        if (t < PDIM)
            out[(size_t)idx * PDIM + t] = red[0][t] + red[1][t] + red[2][t] + red[3][t] + bp2[t];
        __syncthreads();
    }
}

extern "C" void kernel_launch(void* const* d_in, const int* in_sizes, int n_in,
                              void* d_out, int out_size, void* d_ws, size_t ws_size,
                              hipStream_t stream) {
    const float* x   = (const float*)d_in[0];
    const float* W1s = (const float*)d_in[1];
    const float* b1s = (const float*)d_in[2];
    const float* W2s = (const float*)d_in[3];
    const float* b2s = (const float*)d_in[4];
    const float* Wp1 = (const float*)d_in[5];
    const float* bp1 = (const float*)d_in[6];
    const float* Wp2 = (const float*)d_in[7];
    const float* bp2 = (const float*)d_in[8];

    char* ws = (char*)d_ws;
    int*   counters = (int*)(ws + CANDCNT_OFF);   // [0]=candCnt
    int*   candCnt  = counters;
    int*   candIdx  = (int*)(ws + CANDIDX_OFF);
    int*   candSlot = (int*)(ws + CANDSLOT_OFF);
    float* hpart    = (float*)(ws + HPART_OFF);
    float* ha       = hpart + (size_t)KSPLIT * M_ROWS * HDIM;
    float* hb       = ha + (size_t)MAXC * HDIM;
    float* out = (float*)d_out;

    dim3 g(M_ROWS / 64, HDIM / 64, KSPLIT);
    gemm_k_kernel<<<g, 256, 0, stream>>>(x, W1s, hpart, counters);

    span_cand_kernel<<<M_ROWS, 256, 0, stream>>>(hpart, b1s, W2s, b2s,
                                                 candCnt, candIdx, candSlot);

    hab_kernel<<<2048, 256, 0, stream>>>(x, Wp1, candCnt, candIdx, ha, hb);

    pair_kernel<<<512, 256, 0, stream>>>(ha, hb, bp1, Wp2, bp2, candSlot, out);
}

// Round 9
// 140.559 us; speedup vs baseline: 1.0416x; 1.0416x over previous
//
#include <hip/hip_runtime.h>
#include <hip/hip_bf16.h>

// B=4, S=256, H=768, P=54.
// out[b,i,j,p] = valid ? relu(ha[b,i]+hb[b,j]+bp1) . Wp2[p] + bp2[p] : 0
// valid = cand[i] & cand[j] & i!=j; cand = (relu(x W1^T + b1) . W2[0] + b2[0]) > 0.5
// cand rate ~1% -> sparse pairs.
// R1: per-CU-BW-bound hab -> k-split. R2: split-K gemm, stride-68 LDS.
// R3: 139.8. R4/R5: multi-change regressions. R6: coop fusion disaster (340us)
//     BUT calibrated harness overhead: fills+restores ≈ 96us/iter FIXED.
// R7: 137.5 BEST (R3 + counter-zero fold). R8: fused-zero pair = +9 REGRESSION
//     (in-kernel zeroing pays the same write-BW floor, loses optimized fill).
// R9: restore R7 verbatim + ONE change: KSPLIT 4->8 (1536 blk = 6/CU) to test
//     whether gemm (~17us, biggest over-floor item) is barrier/occupancy-bound.

#define M_ROWS 1024
#define HDIM 768
#define PDIM 54
#define MAXC 256            // candidate slot cap (actual nc ~27)
#define KCHUNK 16
#define NKC (HDIM / KCHUNK) // 48
#define KSPLIT 8
#define KSEG (HDIM / KSPLIT) // 96

// ---- workspace layout (bytes) ----
#define CANDCNT_OFF  0
#define PAIRCNT_OFF  4
#define CANDIDX_OFF  8192        // MAXC int
#define CANDSLOT_OFF 12288       // 1024 int (fully written each call)
#define PAIR_OFF     16384       // up to 261120 int
#define HPART_OFF    1064960     // KSPLIT*1024*768 f32 = 24 MB

// ================= split-K GEMM =================
// 64x64 tile, K-seg 96, 256 thr, 4x4 micro. hpart[z][m][n] = partial x.W1^T.
// Block (0,0,0) threads 0/1 zero candCnt/pairCnt (ws is 0xAA-poisoned).
__global__ __launch_bounds__(256) void gemm_k_kernel(
    const float* __restrict__ x, const float* __restrict__ W1,
    float* __restrict__ hpart, int* __restrict__ counters)
{
    __shared__ float As[16][68];
    __shared__ float Bs[16][68];

    if (blockIdx.x == 0 && blockIdx.y == 0 && blockIdx.z == 0 && threadIdx.x < 2)
        counters[threadIdx.x] = 0;

    const int m0 = blockIdx.x * 64;
    const int n0 = blockIdx.y * 64;
    const int kb = blockIdx.z * KSEG;
    const int t  = threadIdx.x;
    const int tm = t & 15;
    const int tn = t >> 4;
    const int r  = t >> 2;        // 0..63
    const int c4 = (t & 3) * 4;   // 0,4,8,12

    float acc[4][4] = {};

    for (int k0 = kb; k0 < kb + KSEG; k0 += 16) {
        float4 av = *(const float4*)(x  + (size_t)(m0 + r) * HDIM + k0 + c4);
        float4 bv = *(const float4*)(W1 + (size_t)(n0 + r) * HDIM + k0 + c4);
        As[c4+0][r] = av.x; As[c4+1][r] = av.y; As[c4+2][r] = av.z; As[c4+3][r] = av.w;
        Bs[c4+0][r] = bv.x; Bs[c4+1][r] = bv.y; Bs[c4+2][r] = bv.z; Bs[c4+3][r] = bv.w;
        __syncthreads();
        #pragma unroll
        for (int kk = 0; kk < 16; ++kk) {
            float a[4], b[4];
            #pragma unroll
            for (int i = 0; i < 4; ++i) a[i] = As[kk][tm * 4 + i];
            #pragma unroll
            for (int j = 0; j < 4; ++j) b[j] = Bs[kk][tn * 4 + j];
            #pragma unroll
            for (int i = 0; i < 4; ++i)
                #pragma unroll
                for (int j = 0; j < 4; ++j)
                    acc[i][j] += a[i] * b[j];
        }
        __syncthreads();
    }

    float* dst = hpart + (size_t)blockIdx.z * (M_ROWS * HDIM);
    #pragma unroll
    for (int i = 0; i < 4; ++i) {
        float4 v = make_float4(acc[i][0], acc[i][1], acc[i][2], acc[i][3]);
        *(float4*)(dst + (size_t)(m0 + tm * 4 + i) * HDIM + n0 + tn * 4) = v;
    }
}

// reduce KSPLIT partials, relu.w2, decide cand. One block per row m.
__global__ __launch_bounds__(256) void span_cand_kernel(
    const float* __restrict__ hpart, const float* __restrict__ b1,
    const float* __restrict__ w2row, const float* __restrict__ b2,
    int* __restrict__ candCount, int* __restrict__ candIdx,
    int* __restrict__ candSlot)
{
    const int m = blockIdx.x;
    const int t = threadIdx.x;
    float p = 0.f;
    for (int n = t; n < HDIM; n += 256) {
        float v = 0.f;
        #pragma unroll
        for (int z = 0; z < KSPLIT; ++z)
            v += hpart[(size_t)z * (M_ROWS * HDIM) + (size_t)m * HDIM + n];
        v += b1[n];
        v = v > 0.f ? v : 0.f;
        p += v * w2row[n];
    }
    __shared__ float wred[4];
    #pragma unroll
    for (int off = 32; off > 0; off >>= 1) p += __shfl_down(p, off, 64);
    if ((t & 63) == 0) wred[t >> 6] = p;
    __syncthreads();
    if (t == 0) {
        float s = wred[0] + wred[1] + wred[2] + wred[3] + b2[0];
        if (s > 0.5f) {
            int sl = atomicAdd(candCount, 1);
            if (sl < MAXC) { candIdx[sl] = m; candSlot[m] = sl; }
            else candSlot[m] = -1;
        } else {
            candSlot[m] = -1;
        }
    }
}

// ================= hab: k-split across blocks (R7-proven) =================
__global__ __launch_bounds__(256) void hab_kernel(
    const float* __restrict__ x, const float* __restrict__ Wp1,
    const int* __restrict__ candCount, const int* __restrict__ candIdx,
    float* __restrict__ ha, float* __restrict__ hb)
{
    __shared__ float xs[HDIM];
    __shared__ float red[2][KCHUNK][17];
    int nc = *candCount; if (nc > MAXC) nc = MAXC;
    const int nitems = nc * NKC;
    const int kk  = threadIdx.x >> 4;
    const int hb0 = (threadIdx.x & 15) * 4;

    for (int item = blockIdx.x; item < nitems; item += gridDim.x) {
        int slot = item / NKC;
        int kc   = item % NKC;
        int row  = candIdx[slot];

        for (int h = threadIdx.x; h < HDIM; h += 256)
            xs[h] = x[(size_t)row * HDIM + h];
        __syncthreads();

        int k = kc * KCHUNK + kk;
        const float* wr = Wp1 + (size_t)k * (2 * HDIM);
        float sa = 0.f, sb = 0.f;
        #pragma unroll
        for (int h = hb0; h < HDIM; h += 64) {
            float4 xv = *(const float4*)(xs + h);
            float4 wa = *(const float4*)(wr + h);
            float4 wb = *(const float4*)(wr + HDIM + h);
            sa += xv.x * wa.x + xv.y * wa.y + xv.z * wa.z + xv.w * wa.w;
            sb += xv.x * wb.x + xv.y * wb.y + xv.z * wb.z + xv.w * wb.w;
        }
        red[0][kk][threadIdx.x & 15] = sa;
        red[1][kk][threadIdx.x & 15] = sb;
        __syncthreads();

        if (threadIdx.x < 32) {
            int which = threadIdx.x >> 4;
            int kk2   = threadIdx.x & 15;
            float s = 0.f;
            #pragma unroll
            for (int g = 0; g < 16; ++g) s += red[which][kk2][g];
            float* dst = which == 0 ? ha : hb;
            dst[(size_t)slot * HDIM + kc * KCHUNK + kk2] = s;
        }
        __syncthreads();
    }
}

// ================= build valid pair list (R7-proven) =================
__global__ void pairs_kernel(const int* __restrict__ candSlot,
                             int* __restrict__ pairCount, int* __restrict__ pairList)
{
    int idx = blockIdx.x * 256 + threadIdx.x;
    int b = idx >> 16;
    int i = (idx >> 8) & 255;
    int j = idx & 255;
    if (i == j) return;
    if (candSlot[b * 256 + i] >= 0 && candSlot[b * 256 + j] >= 0) {
        int p = atomicAdd(pairCount, 1);
        pairList[p] = idx;
    }
}

// ================= sparse pair logits (R7-proven) =================
__global__ __launch_bounds__(256) void pair_kernel(
    const float* __restrict__ ha, const float* __restrict__ hb,
    const float* __restrict__ bp1, const float* __restrict__ Wp2,
    const float* __restrict__ bp2, const int* __restrict__ candSlot,
    const int* __restrict__ pairCount, const int* __restrict__ pairList,
    float* __restrict__ out)
{
    __shared__ float v[HDIM];
    __shared__ float red[4][PDIM + 2];
    const int np = *pairCount;
    const int t = threadIdx.x;
    for (int p = blockIdx.x; p < np; p += gridDim.x) {
        int idx = pairList[p];
        int b = idx >> 16;
        int i = (idx >> 8) & 255;
        int j = idx & 255;
        int si = candSlot[b * 256 + i];
        int sj = candSlot[b * 256 + j];
        if (t < 192) {
            float4 a4 = *(const float4*)(ha + (size_t)si * HDIM + t * 4);
            float4 b4 = *(const float4*)(hb + (size_t)sj * HDIM + t * 4);
            float4 c4 = *(const float4*)(bp1 + t * 4);
            float4 r;
            r.x = a4.x + b4.x + c4.x; r.x = r.x > 0.f ? r.x : 0.f;
            r.y = a4.y + b4.y + c4.y; r.y = r.y > 0.f ? r.y : 0.f;
            r.z = a4.z + b4.z + c4.z; r.z = r.z > 0.f ? r.z : 0.f;
            r.w = a4.w + b4.w + c4.w; r.w = r.w > 0.f ? r.w : 0.f;
            *(float4*)(v + t * 4) = r;
        }
        __syncthreads();
        if (t < 216) {
            int pp  = t % PDIM;
            int seg = t / PDIM;               // 0..3, h-range 192 each
            const float* w = Wp2 + (size_t)pp * HDIM + seg * 192;
            const float* vv = v + seg * 192;
            float s = 0.f;
            for (int h = 0; h < 192; h += 4) {
                float4 a = *(const float4*)(vv + h);
                float4 b2_ = *(const float4*)(w + h);
                s += a.x * b2_.x + a.y * b2_.y + a.z * b2_.z + a.w * b2_.w;
            }
            red[seg][pp] = s;
        }
        __syncthreads();
        if (t < PDIM)
            out[(size_t)idx * PDIM + t] = red[0][t] + red[1][t] + red[2][t] + red[3][t] + bp2[t];
        __syncthreads();
    }
}

extern "C" void kernel_launch(void* const* d_in, const int* in_sizes, int n_in,
                              void* d_out, int out_size, void* d_ws, size_t ws_size,
                              hipStream_t stream) {
    const float* x   = (const float*)d_in[0];
    const float* W1s = (const float*)d_in[1];
    const float* b1s = (const float*)d_in[2];
    const float* W2s = (const float*)d_in[3];
    const float* b2s = (const float*)d_in[4];
    const float* Wp1 = (const float*)d_in[5];
    const float* bp1 = (const float*)d_in[6];
    const float* Wp2 = (const float*)d_in[7];
    const float* bp2 = (const float*)d_in[8];

    char* ws = (char*)d_ws;
    int*   counters = (int*)(ws + CANDCNT_OFF);   // [0]=candCnt, [1]=pairCnt
    int*   candCnt  = counters;
    int*   pairCnt  = counters + 1;
    int*   candIdx  = (int*)(ws + CANDIDX_OFF);
    int*   candSlot = (int*)(ws + CANDSLOT_OFF);
    int*   pairList = (int*)(ws + PAIR_OFF);
    float* hpart    = (float*)(ws + HPART_OFF);
    float* ha       = hpart + (size_t)KSPLIT * M_ROWS * HDIM;
    float* hb       = ha + (size_t)MAXC * HDIM;
    float* out = (float*)d_out;

    // zero output (masked regions must be exactly 0)
    hipMemsetAsync(out, 0, (size_t)out_size * sizeof(float), stream);

    dim3 g(M_ROWS / 64, HDIM / 64, KSPLIT);
    gemm_k_kernel<<<g, 256, 0, stream>>>(x, W1s, hpart, counters);

    span_cand_kernel<<<M_ROWS, 256, 0, stream>>>(hpart, b1s, W2s, b2s,
                                                 candCnt, candIdx, candSlot);

    hab_kernel<<<2048, 256, 0, stream>>>(x, Wp1, candCnt, candIdx, ha, hb);

    pairs_kernel<<<1024, 256, 0, stream>>>(candSlot, pairCnt, pairList);

    pair_kernel<<<512, 256, 0, stream>>>(ha, hb, bp1, Wp2, bp2,
                                         candSlot, pairCnt, pairList, out);
}